// Round 10
// baseline (517.534 us; speedup 1.0000x reference)
//
#include <hip/hip_runtime.h>
#include <hip/hip_bf16.h>
#include <hip/hip_fp16.h>

// ---------------------------------------------------------------------------
// MPNN binding-affinity predictor. R24 = R22 (400us best; R23 nt reverted:
// nt loads pushed 270MB of L3-resident edge reads to HBM, -60us) +
//  - ROW-LOCAL GEMM FUSION: UPD(l) + PQ(l+1) in one kernel (U_next[row] ->
//    PQ[row] has no cross-row dep). U tile parked in LDS (stride 272) and
//    written to global (next-UPD A2 + readout). 5 boundaries deleted.
//    Aggregate stays standalone (R18: serial agg in starved grids is fatal).
// Lessons: no grid barriers/per-block fences (R16/R20); no agg fusion (R18);
// no 128-row tiles (R19); no cache-bypass on producer-consumer data (R23).
// ---------------------------------------------------------------------------

#define HID 256
#define CAP 128  // bucket capacity per node; E/N=16 avg (Poisson), 128 is safe

typedef _Float16 h8 __attribute__((ext_vector_type(8)));
typedef float f32x4 __attribute__((ext_vector_type(4)));

__device__ __forceinline__ void unpack_h8(const int4& r, float* f) {
    const __half2* h = reinterpret_cast<const __half2*>(&r);
#pragma unroll
    for (int k = 0; k < 4; ++k) {
        float2 t = __half22float2(h[k]);
        f[2 * k] = t.x;
        f[2 * k + 1] = t.y;
    }
}

__device__ __forceinline__ void unpack_h4(const int2& r, float* f) {
    const __half2* h = reinterpret_cast<const __half2*>(&r);
    float2 t0 = __half22float2(h[0]);
    float2 t1 = __half22float2(h[1]);
    f[0] = t0.x; f[1] = t0.y; f[2] = t1.x; f[3] = t1.y;
}

// async global -> LDS 16B DMA; dest wave-uniform, lane i lands at dest+16*i
__device__ __forceinline__ void gld16(const void* g, void* l) {
    __builtin_amdgcn_global_load_lds(
        (const __attribute__((address_space(1))) void*)g,
        (__attribute__((address_space(3))) void*)l, 16, 0, 0);
}

// XOR swizzle of 16B k-segments per row; fragment reads <=2-way (free)
__device__ __forceinline__ int swz(int row) { return (row + (row >> 2)) & 3; }

// ------------------------ weight convert -----------------------------------
// src [Kreal, srcN] fp32 row-major -> dst [srcN][dstStride] fp16 (transposed).

struct CDesc {
    const float* src;
    __half* dst;
    int Kreal, Kpad, srcN, tile0, dstStride;
};
struct CTab {
    CDesc d[8];
    int nd;
};

__device__ void convert_body(const CTab& tab, int bid) {
    int idx = 0;
    for (int i = 1; i < tab.nd; ++i)
        if (tab.d[i].tile0 <= bid) idx = i;
    const CDesc d = tab.d[idx];
    const int q = bid - d.tile0;
    const int ntN = d.srcN >> 6;
    const int kb = (q / ntN) * 32;
    const int nb = (q % ntN) * 64;
    const int n = nb + (threadIdx.x & 63);
    const int k0 = kb + (threadIdx.x >> 6) * 8;
    h8 v;
#pragma unroll
    for (int j = 0; j < 8; ++j) {
        int k = k0 + j;
        v[j] = (_Float16)((k < d.Kreal) ? d.src[(size_t)k * d.srcN + n] : 0.f);
    }
    *reinterpret_cast<h8*>(&d.dst[(size_t)n * d.dstStride + k0]) = v;
}

// ----------------------- folded bias vectors -------------------------------

struct BDesc { float* out; const float* base; const float* v1; const float* B1;
               const float* v2; const float* B2; };
struct BTab { BDesc d[31]; };

// ------------------- batched fold GEMM tile --------------------------------
// M^T[n][k] = sum_j srcA^T[n][j] * U2[k][j]  (srcA fp32 [256 j][256 n], read
// transposed+cvt in-stage; U2 fp32 [256 k][256 j], cvt in-stage). Writes fp16
// plane at dst[n*stride + k].

#define ASTR 40

struct FDesc { const float* U2; const float* srcA; __half* dst; int stride; };
struct FTab { FDesc d[22]; };

__device__ void fold_tile(unsigned char* ldsraw, const FDesc& dd, int t4) {
    _Float16* Ah = (_Float16*)ldsraw;
    _Float16* Bh = (_Float16*)(ldsraw + 64 * ASTR * 2);
    const int rowBase = (t4 >> 2) * 64;
    const int colBase = (t4 & 3) * 64;

    const int tid = threadIdx.x;
    const int lane = tid & 63;
    const int wave = tid >> 6;
    const int waveM = (wave >> 1) * 32;
    const int waveN = (wave & 1) * 32;
    const int m0 = lane & 15;
    const int quad = lane >> 4;
    const int sr = tid >> 2;
    const int sseg = tid & 3;

    const f32x4 z = {0.f, 0.f, 0.f, 0.f};
    f32x4 acc[2][2] = {{z, z}, {z, z}};

    for (int kb = 0; kb < 256; kb += 32) {
        {
            const float* Ap = dd.srcA + (size_t)(kb + sseg * 8) * 256 + rowBase + sr;
            h8 v;
#pragma unroll
            for (int j = 0; j < 8; ++j) v[j] = (_Float16)Ap[(size_t)j * 256];
            *reinterpret_cast<h8*>(&Ah[sr * ASTR + sseg * 8]) = v;
        }
        {
            const float* Bp = dd.U2 + (size_t)(colBase + sr) * 256 + kb + sseg * 8;
            float4 u0 = *reinterpret_cast<const float4*>(Bp);
            float4 u1 = *reinterpret_cast<const float4*>(Bp + 4);
            h8 v;
            v[0] = (_Float16)u0.x; v[1] = (_Float16)u0.y;
            v[2] = (_Float16)u0.z; v[3] = (_Float16)u0.w;
            v[4] = (_Float16)u1.x; v[5] = (_Float16)u1.y;
            v[6] = (_Float16)u1.z; v[7] = (_Float16)u1.w;
            *reinterpret_cast<h8*>(&Bh[sr * ASTR + sseg * 8]) = v;
        }
        __syncthreads();

        const h8 a0 = *reinterpret_cast<const h8*>(&Ah[(waveM + m0) * ASTR + quad * 8]);
        const h8 a1 = *reinterpret_cast<const h8*>(&Ah[(waveM + 16 + m0) * ASTR + quad * 8]);
        const h8 b0 = *reinterpret_cast<const h8*>(&Bh[(waveN + m0) * ASTR + quad * 8]);
        const h8 b1 = *reinterpret_cast<const h8*>(&Bh[(waveN + 16 + m0) * ASTR + quad * 8]);

        acc[0][0] = __builtin_amdgcn_mfma_f32_16x16x32_f16(a0, b0, acc[0][0], 0, 0, 0);
        acc[0][1] = __builtin_amdgcn_mfma_f32_16x16x32_f16(a0, b1, acc[0][1], 0, 0, 0);
        acc[1][0] = __builtin_amdgcn_mfma_f32_16x16x32_f16(a1, b0, acc[1][0], 0, 0, 0);
        acc[1][1] = __builtin_amdgcn_mfma_f32_16x16x32_f16(a1, b1, acc[1][1], 0, 0, 0);

        __syncthreads();
    }

#pragma unroll
    for (int tm = 0; tm < 2; ++tm)
#pragma unroll
        for (int reg = 0; reg < 4; ++reg) {
            int n = rowBase + waveM + tm * 16 + quad * 4 + reg;
#pragma unroll
            for (int tn = 0; tn < 2; ++tn) {
                int k = colBase + waveN + tn * 16 + m0;
                dd.dst[(size_t)n * dd.stride + k] = __float2half_rn(acc[tm][tn][reg]);
            }
        }
}

// ----------------------- embed tile (self-converting) ----------------------
// out[row][col] = sum_{k<62} atom[row][k] * emb_w[k][col] + emb_b[col].

__device__ void embed_tile(unsigned char* ldsraw, int bx, int by,
                           const float* __restrict__ atom,
                           const float* __restrict__ emb_w,
                           const float* __restrict__ emb_b,
                           __half* __restrict__ outX, int M) {
    _Float16* Ah = (_Float16*)ldsraw;
    _Float16* Bh = (_Float16*)(ldsraw + 64 * ASTR * 2);
    const int rowBase = bx * 64;
    const int colBase = by * 64;

    const int tid = threadIdx.x;
    const int lane = tid & 63;
    const int wave = tid >> 6;
    const int waveM = (wave >> 1) * 32;
    const int waveN = (wave & 1) * 32;
    const int m0 = lane & 15;
    const int quad = lane >> 4;
    const int sr = tid >> 2;
    const int sseg = tid & 3;

    const f32x4 z = {0.f, 0.f, 0.f, 0.f};
    f32x4 acc[2][2] = {{z, z}, {z, z}};

    for (int kb = 0; kb < 64; kb += 32) {
        {
            const int arow = min(rowBase + sr, M - 1);
            h8 v;
#pragma unroll
            for (int j = 0; j < 8; ++j) {
                int k = kb + sseg * 8 + j;
                v[j] = (_Float16)((k < 62) ? atom[(size_t)arow * 62 + k] : 0.f);
            }
            *reinterpret_cast<h8*>(&Ah[sr * ASTR + sseg * 8]) = v;
        }
        {
            h8 v;
#pragma unroll
            for (int j = 0; j < 8; ++j) {
                int k = kb + sseg * 8 + j;
                v[j] = (_Float16)((k < 62) ? emb_w[(size_t)k * 256 + colBase + sr] : 0.f);
            }
            *reinterpret_cast<h8*>(&Bh[sr * ASTR + sseg * 8]) = v;
        }
        __syncthreads();

        const h8 a0 = *reinterpret_cast<const h8*>(&Ah[(waveM + m0) * ASTR + quad * 8]);
        const h8 a1 = *reinterpret_cast<const h8*>(&Ah[(waveM + 16 + m0) * ASTR + quad * 8]);
        const h8 b0 = *reinterpret_cast<const h8*>(&Bh[(waveN + m0) * ASTR + quad * 8]);
        const h8 b1 = *reinterpret_cast<const h8*>(&Bh[(waveN + 16 + m0) * ASTR + quad * 8]);

        acc[0][0] = __builtin_amdgcn_mfma_f32_16x16x32_f16(a0, b0, acc[0][0], 0, 0, 0);
        acc[0][1] = __builtin_amdgcn_mfma_f32_16x16x32_f16(a0, b1, acc[0][1], 0, 0, 0);
        acc[1][0] = __builtin_amdgcn_mfma_f32_16x16x32_f16(a1, b0, acc[1][0], 0, 0, 0);
        acc[1][1] = __builtin_amdgcn_mfma_f32_16x16x32_f16(a1, b1, acc[1][1], 0, 0, 0);

        __syncthreads();
    }

#pragma unroll
    for (int tm = 0; tm < 2; ++tm)
#pragma unroll
        for (int reg = 0; reg < 4; ++reg) {
            int row = rowBase + waveM + tm * 16 + quad * 4 + reg;
            if (row >= M) continue;
#pragma unroll
            for (int tn = 0; tn < 2; ++tn) {
                int col = colBase + waveN + tn * 16 + m0;
                outX[(size_t)row * 256 + col] =
                    __float2half_rn(acc[tm][tn][reg] + emb_b[col]);
            }
        }
}

// ---- K2: scatter(buckets) + fold-direct + bias vecs + converts + embed ----

__global__ __launch_bounds__(256) void setup_kernel(
    const int* __restrict__ src, const int* __restrict__ dst,
    int* __restrict__ cnt, int* __restrict__ csr_src,
    const float* __restrict__ ef, __half* __restrict__ ef8, int E, int sblocks,
    FTab ft, BTab bt, int fblocks, int bblocks, CTab ct, int cblocks,
    const float* __restrict__ atom, const float* __restrict__ emb_w,
    const float* __restrict__ emb_b, __half* __restrict__ outX,
    int M, int mblk64) {
    __shared__ __align__(16) unsigned char lds[16384];
    int b = blockIdx.x;
    if (b < sblocks) {
        int i = b * 256 + (int)threadIdx.x;
        if (i < E) {
            int d = dst[i];
            int pos = atomicAdd(&cnt[d], 1);
            size_t idx = (size_t)d * CAP + pos;
            csr_src[idx] = src[i];
            const float* s6 = ef + (size_t)i * 6;
            unsigned short h[8];
#pragma unroll
            for (int j = 0; j < 6; ++j) h[j] = __half_as_ushort(__float2half_rn(s6[j]));
            h[6] = 0; h[7] = 0;
            int4 pk;
            pk.x = (int)(h[0] | ((unsigned)h[1] << 16));
            pk.y = (int)(h[2] | ((unsigned)h[3] << 16));
            pk.z = (int)(h[4] | ((unsigned)h[5] << 16));
            pk.w = (int)(h[6] | ((unsigned)h[7] << 16));
            *reinterpret_cast<int4*>(ef8 + idx * 8) = pk;
        }
        return;
    }
    b -= sblocks;
    if (b < fblocks) {
        fold_tile(lds, ft.d[b >> 4], b & 15);
        return;
    }
    b -= fblocks;
    if (b < bblocks) {
        const BDesc d = bt.d[b];
        const int j = threadIdx.x;
        float acc = d.base ? d.base[j] : 0.f;
        if (d.v1)
            for (int k = 0; k < 256; ++k) acc = fmaf(d.v1[k], d.B1[(size_t)k * 256 + j], acc);
        if (d.v2)
            for (int k = 0; k < 256; ++k) acc = fmaf(d.v2[k], d.B2[(size_t)k * 256 + j], acc);
        d.out[j] = acc;
        return;
    }
    b -= bblocks;
    if (b < cblocks) {
        convert_body(ct, b);
        return;
    }
    b -= cblocks;
    embed_tile(lds, b % mblk64, b / mblk64, atom, emb_w, emb_b, outX, M);
}

// ------------------------------ MFMA GEMM ----------------------------------
// C = act( [A|A2]@W + bias + rowscale.*bias2 ), fp16 in/out, fp32 acc.
// Tile 64 x (TN*32), BK=32, 4 waves 2x2. Double-buffered K-loop.

template <int TN>
__global__ __launch_bounds__(256) void mfma_gemm(
    const __half* __restrict__ A, int lda, const __half* __restrict__ A2,
    const __half* __restrict__ W, int K,
    const float* __restrict__ bias, const float* __restrict__ bias2,
    const float* __restrict__ rowscale,
    __half* __restrict__ C, int M, int Nc, int do_relu) {
    constexpr int BUF = 4096 + TN * 2048;
    __shared__ __align__(16) unsigned char lds[2 * BUF];

    const int tid = threadIdx.x;
    const int lane = tid & 63;
    const int wave = tid >> 6;
    const int m0 = lane & 15;
    const int quad = lane >> 4;
    const int waveM = (wave >> 1) * 32;
    const int waveN = (wave & 1) * (TN * 16);
    const int rowBase = blockIdx.x * 64;
    const int colBase = blockIdx.y * (TN * 32);

    const int sa_r = tid >> 2;
    const int sa_ks = (tid & 3) ^ swz(sa_r);
    const int sa_row = min(rowBase + sa_r, M - 1);
    const int sb_r1 = sa_r + 64;
    const int sb_ks1 = (tid & 3) ^ swz(sb_r1);

    int aoff[2], boff[TN];
#pragma unroll
    for (int tm = 0; tm < 2; ++tm) {
        int r = waveM + tm * 16 + m0;
        aoff[tm] = ((r << 2) + (quad ^ swz(r))) << 4;
    }
#pragma unroll
    for (int tn = 0; tn < TN; ++tn) {
        int r = waveN + tn * 16 + m0;
        boff[tn] = 4096 + (((r << 2) + (quad ^ swz(r))) << 4);
    }

    const f32x4 z = {0.f, 0.f, 0.f, 0.f};
    f32x4 acc[2][TN];
#pragma unroll
    for (int tm = 0; tm < 2; ++tm)
#pragma unroll
        for (int tn = 0; tn < TN; ++tn) acc[tm][tn] = z;

    const __half* ga = A + (size_t)sa_row * lda + sa_ks * 8;
    const __half* ga2 = A2 ? A2 + (size_t)sa_row * lda + sa_ks * 8 : nullptr;
    const __half* gb0 = W + (size_t)(colBase + sa_r) * K + sa_ks * 8;
    const __half* gb1 = W + (size_t)(colBase + sb_r1) * K + sb_ks1 * 8;

    auto issue = [&](int p, int kb) {
        unsigned char* base = lds + p * BUF;
        const __half* as = (A2 && kb >= 256) ? (ga2 + (kb - 256)) : (ga + kb);
        gld16(as, base + wave * 1024);
        gld16(gb0 + kb, base + 4096 + wave * 1024);
        if constexpr (TN == 4) gld16(gb1 + kb, base + 8192 + wave * 1024);
    };

    issue(0, 0);
    int p = 0;
    for (int kb = 0; kb < K; kb += 32) {
        const bool has_next = (kb + 32 < K);
        if (has_next) issue(p ^ 1, kb + 32);
        if (has_next) {
            if constexpr (TN == 4)
                asm volatile("s_waitcnt vmcnt(3)" ::: "memory");
            else
                asm volatile("s_waitcnt vmcnt(2)" ::: "memory");
        } else {
            asm volatile("s_waitcnt vmcnt(0)" ::: "memory");
        }
        asm volatile("s_barrier" ::: "memory");

        const unsigned char* base = lds + p * BUF;
        h8 ah[2], bh[TN];
#pragma unroll
        for (int tm = 0; tm < 2; ++tm)
            ah[tm] = *reinterpret_cast<const h8*>(base + aoff[tm]);
#pragma unroll
        for (int tn = 0; tn < TN; ++tn)
            bh[tn] = *reinterpret_cast<const h8*>(base + boff[tn]);
#pragma unroll
        for (int tm = 0; tm < 2; ++tm)
#pragma unroll
            for (int tn = 0; tn < TN; ++tn)
                acc[tm][tn] = __builtin_amdgcn_mfma_f32_16x16x32_f16(
                    ah[tm], bh[tn], acc[tm][tn], 0, 0, 0);
        asm volatile("s_waitcnt lgkmcnt(0)" ::: "memory");
        asm volatile("s_barrier" ::: "memory");
        p ^= 1;
    }

    // epilogue
    float cb[TN], db[TN];
    int col[TN];
#pragma unroll
    for (int tn = 0; tn < TN; ++tn) {
        col[tn] = colBase + waveN + tn * 16 + m0;
        cb[tn] = bias ? bias[col[tn]] : 0.f;
        db[tn] = bias2 ? bias2[col[tn]] : 0.f;
    }
#pragma unroll
    for (int tm = 0; tm < 2; ++tm) {
#pragma unroll
        for (int reg = 0; reg < 4; ++reg) {
            int row = rowBase + waveM + tm * 16 + quad * 4 + reg;
            if (row >= M) continue;
            float rs = rowscale ? rowscale[row] : 0.0f;
#pragma unroll
            for (int tn = 0; tn < TN; ++tn) {
                float v = acc[tm][tn][reg] + cb[tn] + rs * db[tn];
                if (do_relu) v = fmaxf(v, 0.f);
                C[(size_t)row * Nc + col[tn]] = __float2half_rn(v);
            }
        }
    }
}

// ------------------- fused UPD(l) + PQ(l+1) kernel --------------------------
// Row-local chain: U[row] = relu([Hagg|Uprev]@wUPD + bias + deg*bias2) is the
// only input PQ(l+1)[row] needs. Block = 64 rows, 256 thr (4 waves, 2x2).
// Phase B: 4 x 64-col passes (K=512) -> U to LDS TAH (stride 272) + global.
// Phase C: 8 x 64-col passes (K=256), A from TAH, B dbuf via gld16.

__global__ __launch_bounds__(256) void upd_pq_kernel(
    const __half* __restrict__ Hagg, const __half* __restrict__ Uprev,
    const __half* __restrict__ wUPD,
    const float* __restrict__ bias, const float* __restrict__ bias2,
    const float* __restrict__ degf,
    __half* __restrict__ Unext,
    const __half* __restrict__ wPQn, const float* __restrict__ b512n,
    __half* __restrict__ PQ, int M) {
    __shared__ __align__(16) unsigned char lds[16384 + 64 * 272 * 2];
    _Float16* TAH = (_Float16*)(lds + 16384);

    const int tid = threadIdx.x;
    const int lane = tid & 63;
    const int wave = tid >> 6;
    const int m0 = lane & 15;
    const int quad = lane >> 4;
    const int waveM = (wave >> 1) * 32;
    const int waveN = (wave & 1) * 32;
    const int rowBase = (int)blockIdx.x * 64;

    const int sa_r = tid >> 2;
    const int sa_ks = (tid & 3) ^ swz(sa_r);
    const int sa_row = min(rowBase + sa_r, M - 1);

    int aoff[2], boff[2];
#pragma unroll
    for (int tm = 0; tm < 2; ++tm) {
        int r = waveM + tm * 16 + m0;
        aoff[tm] = ((r << 2) + (quad ^ swz(r))) << 4;
    }
#pragma unroll
    for (int tn = 0; tn < 2; ++tn) {
        int r = waveN + tn * 16 + m0;
        boff[tn] = 4096 + (((r << 2) + (quad ^ swz(r))) << 4);
    }

    const f32x4 z = {0.f, 0.f, 0.f, 0.f};
    const __half* gaH = Hagg + (size_t)sa_row * 256 + sa_ks * 8;
    const __half* gaU = Uprev + (size_t)sa_row * 256 + sa_ks * 8;

    // ---------------- Phase B: U = relu([Hagg|Uprev]@wUPD + b + deg*b2) ----
    for (int by4 = 0; by4 < 4; ++by4) {
        const int colBase = by4 * 64;
        const __half* gb0 = wUPD + (size_t)(colBase + sa_r) * 512 + sa_ks * 8;
        f32x4 acc[2][2] = {{z, z}, {z, z}};

        auto issue = [&](int p, int kb) {
            unsigned char* base = lds + p * 8192;
            const __half* as = (kb >= 256) ? (gaU + (kb - 256)) : (gaH + kb);
            gld16(as, base + wave * 1024);
            gld16(gb0 + kb, base + 4096 + wave * 1024);
        };
        issue(0, 0);
        int p = 0;
        for (int kb = 0; kb < 512; kb += 32) {
            const bool hn = kb + 32 < 512;
            if (hn) issue(p ^ 1, kb + 32);
            if (hn) asm volatile("s_waitcnt vmcnt(2)" ::: "memory");
            else    asm volatile("s_waitcnt vmcnt(0)" ::: "memory");
            asm volatile("s_barrier" ::: "memory");
            const unsigned char* base = lds + p * 8192;
            h8 ah[2], bh[2];
#pragma unroll
            for (int tm = 0; tm < 2; ++tm)
                ah[tm] = *reinterpret_cast<const h8*>(base + aoff[tm]);
#pragma unroll
            for (int tn = 0; tn < 2; ++tn)
                bh[tn] = *reinterpret_cast<const h8*>(base + boff[tn]);
#pragma unroll
            for (int tm = 0; tm < 2; ++tm)
#pragma unroll
                for (int tn = 0; tn < 2; ++tn)
                    acc[tm][tn] = __builtin_amdgcn_mfma_f32_16x16x32_f16(
                        ah[tm], bh[tn], acc[tm][tn], 0, 0, 0);
            asm volatile("s_waitcnt lgkmcnt(0)" ::: "memory");
            asm volatile("s_barrier" ::: "memory");
            p ^= 1;
        }
        // epilogue -> TAH (+ global Unext)
        float cb[2], db[2];
        int col[2];
#pragma unroll
        for (int tn = 0; tn < 2; ++tn) {
            col[tn] = colBase + waveN + tn * 16 + m0;
            cb[tn] = bias[col[tn]];
            db[tn] = bias2[col[tn]];
        }
#pragma unroll
        for (int tm = 0; tm < 2; ++tm)
#pragma unroll
            for (int reg = 0; reg < 4; ++reg) {
                const int lrow = waveM + tm * 16 + quad * 4 + reg;
                const int row = rowBase + lrow;
                const float rs = degf[min(row, M - 1)];
#pragma unroll
                for (int tn = 0; tn < 2; ++tn) {
                    float v = acc[tm][tn][reg] + cb[tn] + rs * db[tn];
                    v = fmaxf(v, 0.f);
                    TAH[lrow * 272 + col[tn]] = (_Float16)v;
                    if (row < M)
                        Unext[(size_t)row * 256 + col[tn]] = __float2half_rn(v);
                }
            }
    }
    __syncthreads();

    // ---------------- Phase C: PQ = U(TAH) @ wPQn + b512n ------------------
    for (int bp = 0; bp < 8; ++bp) {
        const int colBase = bp * 64;
        const __half* gb0 = wPQn + (size_t)(colBase + sa_r) * 256 + sa_ks * 8;
        f32x4 acc[2][2] = {{z, z}, {z, z}};

        auto issueB = [&](int p, int kb) {
            gld16(gb0 + kb, lds + p * 8192 + 4096 + wave * 1024);
        };
        issueB(0, 0);
        int p = 0;
        for (int kb = 0; kb < 256; kb += 32) {
            const bool hn = kb + 32 < 256;
            if (hn) issueB(p ^ 1, kb + 32);
            if (hn) asm volatile("s_waitcnt vmcnt(1)" ::: "memory");
            else    asm volatile("s_waitcnt vmcnt(0)" ::: "memory");
            asm volatile("s_barrier" ::: "memory");
            const unsigned char* base = lds + p * 8192;
            h8 ah[2], bh[2];
#pragma unroll
            for (int tm = 0; tm < 2; ++tm)
                ah[tm] = *reinterpret_cast<const h8*>(
                    &TAH[(waveM + tm * 16 + m0) * 272 + kb + quad * 8]);
#pragma unroll
            for (int tn = 0; tn < 2; ++tn)
                bh[tn] = *reinterpret_cast<const h8*>(base + boff[tn]);
#pragma unroll
            for (int tm = 0; tm < 2; ++tm)
#pragma unroll
                for (int tn = 0; tn < 2; ++tn)
                    acc[tm][tn] = __builtin_amdgcn_mfma_f32_16x16x32_f16(
                        ah[tm], bh[tn], acc[tm][tn], 0, 0, 0);
            asm volatile("s_waitcnt lgkmcnt(0)" ::: "memory");
            asm volatile("s_barrier" ::: "memory");
            p ^= 1;
        }
        float cb[2];
        int col[2];
#pragma unroll
        for (int tn = 0; tn < 2; ++tn) {
            col[tn] = colBase + waveN + tn * 16 + m0;
            cb[tn] = b512n[col[tn]];
        }
#pragma unroll
        for (int tm = 0; tm < 2; ++tm)
#pragma unroll
            for (int reg = 0; reg < 4; ++reg) {
                const int row = rowBase + waveM + tm * 16 + quad * 4 + reg;
                if (row >= M) continue;
#pragma unroll
                for (int tn = 0; tn < 2; ++tn)
                    PQ[(size_t)row * 512 + col[tn]] =
                        __float2half_rn(acc[tm][tn][reg] + cb[tn]);
            }
    }
}

// --------------------------- edge aggregation ------------------------------
// Hagg[v] = sum_{e=(s,v)} relu(P[s] + Q[v] + ef_e @ W1c); bagg pre-added to
// Q by the PQ GEMM bias. PQ fp16 [N][512]. Bucketed edges: node v's edges at
// [v*CAP, v*CAP+cnt[v]). One wave/node, 4 ch/lane. degf_out on layer 0.

__global__ __launch_bounds__(256) void aggregate_kernel(
    const __half* __restrict__ PQ, const __half* __restrict__ ef8,
    const int* __restrict__ cnt, const int* __restrict__ csr_src,
    const float* __restrict__ W1c, __half* __restrict__ Hagg,
    float* __restrict__ degf_out, int n) {
    const int wave = threadIdx.x >> 6;
    const int lane = threadIdx.x & 63;
    const int node = blockIdx.x * 4 + wave;
    if (node >= n) return;
    const int ch = lane * 4;  // 64 lanes x 4 ch = 256

    float wc[6][4];
#pragma unroll
    for (int k = 0; k < 6; ++k) {
        float4 w0 = *reinterpret_cast<const float4*>(W1c + k * HID + ch);
        wc[k][0] = w0.x; wc[k][1] = w0.y; wc[k][2] = w0.z; wc[k][3] = w0.w;
    }
    float qb[4];
    unpack_h4(*reinterpret_cast<const int2*>(PQ + (size_t)node * 512 + 256 + ch), qb);

    float acc[4] = {0.f, 0.f, 0.f, 0.f};

    auto fma_edge = [&](const int2& praw, const int4& eraw) {
        float p[4], e[8];
        unpack_h4(praw, p);
        unpack_h8(eraw, e);
#pragma unroll
        for (int i = 0; i < 4; ++i) {
            float h = p[i] + qb[i];
            h = fmaf(e[0], wc[0][i], h);
            h = fmaf(e[1], wc[1][i], h);
            h = fmaf(e[2], wc[2][i], h);
            h = fmaf(e[3], wc[3][i], h);
            h = fmaf(e[4], wc[4][i], h);
            h = fmaf(e[5], wc[5][i], h);
            acc[i] += fmaxf(h, 0.f);
        }
    };

    const int beg = node * CAP;
    const int deg = cnt[node];
    const int end = beg + deg;
    if (degf_out && lane == 0) degf_out[node] = (float)deg;
    int j = beg;

    while (j + 6 <= end) {
        int s0 = csr_src[j];
        int s1 = csr_src[j + 1];
        int s2 = csr_src[j + 2];
        int s3 = csr_src[j + 3];
        int s4 = csr_src[j + 4];
        int s5 = csr_src[j + 5];
        int4 e0 = *reinterpret_cast<const int4*>(ef8 + (size_t)j * 8);
        int4 e1 = *reinterpret_cast<const int4*>(ef8 + (size_t)(j + 1) * 8);
        int4 e2 = *reinterpret_cast<const int4*>(ef8 + (size_t)(j + 2) * 8);
        int4 e3 = *reinterpret_cast<const int4*>(ef8 + (size_t)(j + 3) * 8);
        int4 e4 = *reinterpret_cast<const int4*>(ef8 + (size_t)(j + 4) * 8);
        int4 e5 = *reinterpret_cast<const int4*>(ef8 + (size_t)(j + 5) * 8);
        int2 p0 = *reinterpret_cast<const int2*>(PQ + (size_t)s0 * 512 + ch);
        int2 p1 = *reinterpret_cast<const int2*>(PQ + (size_t)s1 * 512 + ch);
        int2 p2 = *reinterpret_cast<const int2*>(PQ + (size_t)s2 * 512 + ch);
        int2 p3 = *reinterpret_cast<const int2*>(PQ + (size_t)s3 * 512 + ch);
        int2 p4 = *reinterpret_cast<const int2*>(PQ + (size_t)s4 * 512 + ch);
        int2 p5 = *reinterpret_cast<const int2*>(PQ + (size_t)s5 * 512 + ch);
        fma_edge(p0, e0);
        fma_edge(p1, e1);
        fma_edge(p2, e2);
        fma_edge(p3, e3);
        fma_edge(p4, e4);
        fma_edge(p5, e5);
        j += 6;
    }
    while (j + 2 <= end) {
        int s0 = csr_src[j];
        int s1 = csr_src[j + 1];
        int4 e0 = *reinterpret_cast<const int4*>(ef8 + (size_t)j * 8);
        int4 e1 = *reinterpret_cast<const int4*>(ef8 + (size_t)(j + 1) * 8);
        int2 p0 = *reinterpret_cast<const int2*>(PQ + (size_t)s0 * 512 + ch);
        int2 p1 = *reinterpret_cast<const int2*>(PQ + (size_t)s1 * 512 + ch);
        fma_edge(p0, e0);
        fma_edge(p1, e1);
        j += 2;
    }
    if (j < end) {
        int s = csr_src[j];
        int4 e = *reinterpret_cast<const int4*>(ef8 + (size_t)j * 8);
        int2 pw = *reinterpret_cast<const int2*>(PQ + (size_t)s * 512 + ch);
        fma_edge(pw, e);
    }

    unsigned short hs[4];
#pragma unroll
    for (int i = 0; i < 4; ++i) hs[i] = __half_as_ushort(__float2half_rn(acc[i]));
    int2 pk;
    pk.x = (int)(hs[0] | ((unsigned)hs[1] << 16));
    pk.y = (int)(hs[2] | ((unsigned)hs[3] << 16));
    *reinterpret_cast<int2*>(Hagg + (size_t)node * HID + ch) = pk;
}

// --------------------------- fused readout ---------------------------------
// h1 = relu(U5@wF + cbF) -> LDS (stride 272 halves); h2 = relu(h1@wR2 + bR2);
// s += h2 . w3 per row; block reduce; atomicAdd; done-counter finalize.

__global__ __launch_bounds__(256) void readout_kernel(
    const __half* __restrict__ U5, const __half* __restrict__ wF,
    const float* __restrict__ cbF, const __half* __restrict__ wR2,
    const float* __restrict__ bR2, const float* __restrict__ w3,
    const float* __restrict__ b3, float* __restrict__ accum,
    int* __restrict__ done, float* __restrict__ outp, int M, int nblocks) {
    __shared__ __align__(16) unsigned char lds[24576 + 64 * 272 * 2];
    _Float16* h1 = (_Float16*)(lds + 24576);

    const int tid = threadIdx.x;
    const int lane = tid & 63;
    const int wave = tid >> 6;
    const int m0 = lane & 15;
    const int quad = lane >> 4;
    const int waveM = (wave >> 1) * 32;
    const int waveN = (wave & 1) * 64;
    const int rowBase = blockIdx.x * 64;

    const int sa_r = tid >> 2;
    const int sa_ks = (tid & 3) ^ swz(sa_r);
    const int sa_row = min(rowBase + sa_r, M - 1);
    const int sb_r1 = sa_r + 64;
    const int sb_ks1 = (tid & 3) ^ swz(sb_r1);

    int aoff[2], boff[4];
#pragma unroll
    for (int tm = 0; tm < 2; ++tm) {
        int r = waveM + tm * 16 + m0;
        aoff[tm] = ((r << 2) + (quad ^ swz(r))) << 4;
    }
#pragma unroll
    for (int tn = 0; tn < 4; ++tn) {
        int r = waveN + tn * 16 + m0;
        boff[tn] = (((r << 2) + (quad ^ swz(r))) << 4);
    }

    constexpr int BUF = 4096 + 4 * 2048;
    const f32x4 z = {0.f, 0.f, 0.f, 0.f};

    for (int half = 0; half < 2; ++half) {
        const __half* W = wF + (size_t)(half * 128) * 256;
        f32x4 acc[2][4] = {{z, z, z, z}, {z, z, z, z}};
        const __half* ga = U5 + (size_t)sa_row * 256 + sa_ks * 8;
        const __half* gb0 = W + (size_t)sa_r * 256 + sa_ks * 8;
        const __half* gb1 = W + (size_t)sb_r1 * 256 + sb_ks1 * 8;

        auto issue = [&](int p, int kb) {
            unsigned char* base = lds + p * BUF;
            gld16(ga + kb, base + wave * 1024);
            gld16(gb0 + kb, base + 4096 + wave * 1024);
            gld16(gb1 + kb, base + 8192 + wave * 1024);
        };
        issue(0, 0);
        int p = 0;
        for (int kb = 0; kb < 256; kb += 32) {
            const bool has_next = (kb + 32 < 256);
            if (has_next) issue(p ^ 1, kb + 32);
            if (has_next) asm volatile("s_waitcnt vmcnt(3)" ::: "memory");
            else asm volatile("s_waitcnt vmcnt(0)" ::: "memory");
            asm volatile("s_barrier" ::: "memory");
            const unsigned char* base = lds + p * BUF;
            h8 ah[2], bh[4];
#pragma unroll
            for (int tm = 0; tm < 2; ++tm)
                ah[tm] = *reinterpret_cast<const h8*>(base + aoff[tm]);
#pragma unroll
            for (int tn = 0; tn < 4; ++tn)
                bh[tn] = *reinterpret_cast<const h8*>(base + 4096 + boff[tn]);
#pragma unroll
            for (int tm = 0; tm < 2; ++tm)
#pragma unroll
                for (int tn = 0; tn < 4; ++tn)
                    acc[tm][tn] = __builtin_amdgcn_mfma_f32_16x16x32_f16(
                        ah[tm], bh[tn], acc[tm][tn], 0, 0, 0);
            asm volatile("s_waitcnt lgkmcnt(0)" ::: "memory");
            asm volatile("s_barrier" ::: "memory");
            p ^= 1;
        }
#pragma unroll
        for (int tm = 0; tm < 2; ++tm)
#pragma unroll
            for (int reg = 0; reg < 4; ++reg) {
                int r = waveM + tm * 16 + quad * 4 + reg;
#pragma unroll
                for (int tn = 0; tn < 4; ++tn) {
                    int c = half * 128 + waveN + tn * 16 + m0;
                    float v = acc[tm][tn][reg] + cbF[c];
                    h1[r * 272 + c] = (_Float16)fmaxf(v, 0.f);
                }
            }
        __syncthreads();
    }

    f32x4 acc2[2][4] = {{z, z, z, z}, {z, z, z, z}};
    auto issueB = [&](int p, int kb) {
        unsigned char* base = lds + p * 8192;
        gld16(wR2 + (size_t)sa_r * 256 + sa_ks * 8 + kb, base + wave * 1024);
        gld16(wR2 + (size_t)sb_r1 * 256 + sb_ks1 * 8 + kb, base + 4096 + wave * 1024);
    };
    issueB(0, 0);
    int p = 0;
    for (int kb = 0; kb < 256; kb += 32) {
        const bool has_next = (kb + 32 < 256);
        if (has_next) issueB(p ^ 1, kb + 32);
        if (has_next) asm volatile("s_waitcnt vmcnt(2)" ::: "memory");
        else asm volatile("s_waitcnt vmcnt(0)" ::: "memory");
        asm volatile("s_barrier" ::: "memory");
        const unsigned char* base = lds + p * 8192;
        h8 ah[2], bh[4];
#pragma unroll
        for (int tm = 0; tm < 2; ++tm)
            ah[tm] = *reinterpret_cast<const h8*>(
                &h1[(waveM + tm * 16 + m0) * 272 + kb + quad * 8]);
#pragma unroll
        for (int tn = 0; tn < 4; ++tn)
            bh[tn] = *reinterpret_cast<const h8*>(base + boff[tn]);
#pragma unroll
        for (int tm = 0; tm < 2; ++tm)
#pragma unroll
            for (int tn = 0; tn < 4; ++tn)
                acc2[tm][tn] = __builtin_amdgcn_mfma_f32_16x16x32_f16(
                    ah[tm], bh[tn], acc2[tm][tn], 0, 0, 0);
        asm volatile("s_waitcnt lgkmcnt(0)" ::: "memory");
        asm volatile("s_barrier" ::: "memory");
        p ^= 1;
    }

    float s = 0.f;
#pragma unroll
    for (int tm = 0; tm < 2; ++tm)
#pragma unroll
        for (int reg = 0; reg < 4; ++reg) {
            int row = rowBase + waveM + tm * 16 + quad * 4 + reg;
            if (row >= M) continue;
#pragma unroll
            for (int tn = 0; tn < 4; ++tn) {
                int c = waveN + tn * 16 + m0;
                float v = acc2[tm][tn][reg] + bR2[c];
                s += fmaxf(v, 0.f) * w3[c];
            }
        }
    __syncthreads();
    float* red = (float*)lds;
    red[tid] = s;
    __syncthreads();
    for (int off = 128; off > 0; off >>= 1) {
        if (tid < off) red[tid] += red[tid + off];
        __syncthreads();
    }
    if (tid == 0) {
        atomicAdd(accum, red[0]);
        __threadfence();
        int old = atomicAdd(done, 1);
        if (old == nblocks - 1) {
            float tot = atomicAdd(accum, 0.0f);
            outp[0] = tot / (float)M + b3[0];
        }
    }
}

// ------------------------------- driver ------------------------------------

extern "C" void kernel_launch(void* const* d_in, const int* in_sizes, int n_in,
                              void* d_out, int out_size, void* d_ws, size_t ws_size,
                              hipStream_t stream) {
    const float* atom   = (const float*)d_in[0];
    const int*   eidx   = (const int*)d_in[1];
    const float* ef     = (const float*)d_in[2];
    const float* emb_w  = (const float*)d_in[3];
    const float* emb_b  = (const float*)d_in[4];
    const float* msg_w1 = (const float*)d_in[5];
    const float* msg_b1 = (const float*)d_in[6];
    const float* msg_w2 = (const float*)d_in[7];
    const float* msg_b2 = (const float*)d_in[8];
    const float* upd_w1 = (const float*)d_in[9];
    const float* upd_b1 = (const float*)d_in[10];
    const float* upd_w2 = (const float*)d_in[11];
    const float* upd_b2 = (const float*)d_in[12];
    const float* r_w1   = (const float*)d_in[13];
    const float* r_b1   = (const float*)d_in[14];
    const float* r_w2   = (const float*)d_in[15];
    const float* r_b2   = (const float*)d_in[16];
    const float* r_w3   = (const float*)d_in[17];
    const float* r_b3   = (const float*)d_in[18];

    const int N = in_sizes[0] / 62;
    const int E = in_sizes[1] / 2;
    const int L = in_sizes[5] / (518 * 256);
    const int* src = eidx;
    const int* dst = eidx + E;

    char* wp = (char*)d_ws;
    auto alloc = [&](size_t bytes) -> void* {
        void* p = (void*)wp;
        wp += (bytes + 255) & ~(size_t)255;
        return p;
    };
    int*   cnt     = (int*)alloc((size_t)N * 4);
    float* accum   = (float*)alloc(256);
    int*   done    = (int*)((char*)accum + 16);
    size_t zero_bytes = (size_t)((char*)accum - (char*)d_ws) + 256;
    float* degf    = (float*)alloc((size_t)N * 4);
    int*   csr_src = (int*)alloc((size_t)N * CAP * 4);
    __half* ef8    = (__half*)alloc((size_t)N * CAP * 8 * 2);

    const int SQ_P = 256 * 256;
    __half* w_r2  = (__half*)alloc((size_t)128 * 256 * 2);
    __half* wF    = (__half*)alloc((size_t)SQ_P * 2);
    __half *wPQ[6], *wUPD[6];
    for (int l = 0; l < L; ++l) {
        wPQ[l]  = (__half*)alloc((size_t)512 * 256 * 2);  // [512 cols][K=256]
        wUPD[l] = (__half*)alloc((size_t)256 * 512 * 2);  // [256 cols][K=512] = [wM3;wR]
    }
    float* bvec = (float*)alloc((size_t)19 * 256 * 4);
    float* b512 = (float*)alloc((size_t)L * 512 * 4);

    __half* bufX0 = (__half*)alloc((size_t)N * HID * 2);
    __half* bufX1 = (__half*)alloc((size_t)N * HID * 2);
    __half* PQ    = (__half*)alloc((size_t)N * 512 * 2);
    __half* HaggH = (__half*)alloc((size_t)N * HID * 2);

    hipMemsetAsync(d_ws, 0, zero_bytes, stream);

    // ---- direct-use converts (run inside K2; consumers are post-K2) ----
    CTab ct;
    int nd = 0, ctiles = 0;
    auto addDesc = [&](const float* s, __half* dh, int Kreal, int Kpad, int srcN,
                       int dstStride) {
        ct.d[nd] = {s, dh, Kreal, Kpad, srcN, ctiles, dstStride};
        ctiles += (Kpad / 32) * (srcN / 64);
        ++nd;
    };
    addDesc(msg_w1, wPQ[0], 256, 256, 256, 256);                     // P l=0
    addDesc(msg_w1 + 256 * 256, wPQ[0] + SQ_P, 256, 256, 256, 256);  // Q l=0
    addDesc(upd_w1, wUPD[0] + 256, 256, 256, 256, 512);              // R l=0 -> hi-K
    addDesc(r_w2, w_r2, 256, 256, 128, 256);
    ct.nd = nd;

    // ---- fold GEMM descriptors (A = raw fp32 source, cvt in-stage) ----
    FTab ft;
    for (int l = 1; l < L; ++l) {
        const float* U2p = upd_w2 + (size_t)(l - 1) * SQ_P;
        ft.d[l - 1] = {U2p, msg_w1 + (size_t)l * 518 * 256, wPQ[l], 256};
        ft.d[4 + l] = {U2p, msg_w1 + (size_t)l * 518 * 256 + 256 * 256,
                       wPQ[l] + SQ_P, 256};
        ft.d[9 + l] = {U2p, upd_w1 + (size_t)l * 512 * 256, wUPD[l] + 256, 512};
    }
    for (int l = 0; l < L; ++l)
        ft.d[15 + l] = {msg_w2 + (size_t)l * SQ_P,
                        upd_w1 + (size_t)l * 512 * 256 + 256 * 256, wUPD[l], 512};
    ft.d[21] = {upd_w2 + (size_t)5 * SQ_P, r_w1, wF, 256};

    BTab bt;
    int nb = 0;
    for (int l = 0; l < L; ++l) {
        const float* ub2p = (l > 0) ? upd_b2 + (size_t)(l - 1) * 256 : nullptr;
        bt.d[nb++] = {b512 + (size_t)l * 512 + 256, msg_b1 + (size_t)l * 256,
                      ub2p, msg_w1 + (size_t)l * 518 * 256,
                      ub2p, msg_w1 + (size_t)l * 518 * 256 + 256 * 256};
        bt.d[nb++] = {b512 + (size_t)l * 512, nullptr, nullptr, nullptr, nullptr, nullptr};
        bt.d[nb++] = {bvec + (size_t)(6 + l) * 256, upd_b1 + (size_t)l * 256,
                      ub2p, upd_w1 + (size_t)l * 512 * 256, nullptr, nullptr};
        bt.d[nb++] = {bvec + (size_t)(12 + l) * 256, nullptr,
                      msg_b2 + (size_t)l * 256, upd_w1 + (size_t)l * 512 * 256 + 256 * 256,
                      nullptr, nullptr};
    }
    bt.d[nb++] = {bvec + (size_t)18 * 256, r_b1, upd_b2 + (size_t)5 * 256, r_w1,
                  nullptr, nullptr};

    // ---- K2: scatter + fold-direct + bias + converts + embed-direct ----
    const int sblocks = (E + 255) / 256;
    const int fblocks = 22 * 16;
    const int mblk64 = (N + 63) / 64;
    const int grid2 = sblocks + fblocks + nb + ctiles + mblk64 * 4;
    setup_kernel<<<grid2, 256, 0, stream>>>(
        src, dst, cnt, csr_src, ef, ef8, E, sblocks,
        ft, bt, fblocks, nb, ct, ctiles,
        atom, emb_w, emb_b, bufX0, N, mblk64);

    dim3 blk(256);

    // PQ0 = U0 @ [M1a|M1b] + [0|bagg]
    mfma_gemm<4><<<dim3(mblk64, 4), blk, 0, stream>>>(
        bufX0, HID, nullptr, wPQ[0], HID,
        b512, nullptr, nullptr, PQ, N, 512, 0);

    // ---- layers: agg -> fused UPD+PQ(next) (last layer: plain UPD) ----
    __half* U_prev = bufX0;
    __half* U_next = bufX1;
    for (int l = 0; l < L; ++l) {
        const float* w1c = msg_w1 + (size_t)l * 518 * 256 + 512 * 256;
        aggregate_kernel<<<(N + 3) / 4, blk, 0, stream>>>(
            PQ, ef8, cnt, csr_src, w1c, HaggH, (l == 0) ? degf : nullptr, N);
        if (l + 1 < L) {
            upd_pq_kernel<<<mblk64, blk, 0, stream>>>(
                HaggH, U_prev, wUPD[l],
                bvec + (size_t)(6 + l) * 256, bvec + (size_t)(12 + l) * 256, degf,
                U_next, wPQ[l + 1], b512 + (size_t)(l + 1) * 512, PQ, N);
        } else {
            mfma_gemm<2><<<dim3(mblk64, 4), blk, 0, stream>>>(
                HaggH, HID, U_prev, wUPD[l], 512,
                bvec + (size_t)(6 + l) * 256, bvec + (size_t)(12 + l) * 256, degf,
                U_next, N, 256, 1);
        }
        __half* t = U_prev; U_prev = U_next; U_next = t;
    }

    // fused readout
    readout_kernel<<<mblk64, blk, 0, stream>>>(
        U_prev, wF, bvec + (size_t)18 * 256, w_r2, r_b2, r_w3, r_b3,
        accum, done, (float*)d_out, N, mblk64);
}

// Round 12
// 398.117 us; speedup vs baseline: 1.3000x; 1.3000x over previous
//
#include <hip/hip_runtime.h>
#include <hip/hip_bf16.h>
#include <hip/hip_fp16.h>

// ---------------------------------------------------------------------------
// MPNN binding-affinity predictor. R26 = R22 verbatim (400us best; R25 run
// was an infra failure, resubmitting unchanged).
// R24 lesson (3rd confirmation): fusing UPD+PQ collapses the grid to N/64=157
// blocks -> 5.9% occupancy, 48us/instance. Column parallelism must stay in
// the grid; GEMM->GEMM fusion destroys it. Dispatch count (21) is at the
// dependency floor; residual ~180us is fixed ~9us/boundary runtime cost
// (R23 proved it's not proportional to dirty-L2 footprint).
// Lessons: no grid barriers/per-block fences (R16/R20); no agg fusion (R18);
// no sub-600-block grids (R19/R24); no cache-bypass on reused data (R23).
// ---------------------------------------------------------------------------

#define HID 256
#define CAP 128  // bucket capacity per node; E/N=16 avg (Poisson), 128 is safe

typedef _Float16 h8 __attribute__((ext_vector_type(8)));
typedef float f32x4 __attribute__((ext_vector_type(4)));

__device__ __forceinline__ void unpack_h8(const int4& r, float* f) {
    const __half2* h = reinterpret_cast<const __half2*>(&r);
#pragma unroll
    for (int k = 0; k < 4; ++k) {
        float2 t = __half22float2(h[k]);
        f[2 * k] = t.x;
        f[2 * k + 1] = t.y;
    }
}

__device__ __forceinline__ void unpack_h4(const int2& r, float* f) {
    const __half2* h = reinterpret_cast<const __half2*>(&r);
    float2 t0 = __half22float2(h[0]);
    float2 t1 = __half22float2(h[1]);
    f[0] = t0.x; f[1] = t0.y; f[2] = t1.x; f[3] = t1.y;
}

// async global -> LDS 16B DMA; dest wave-uniform, lane i lands at dest+16*i
__device__ __forceinline__ void gld16(const void* g, void* l) {
    __builtin_amdgcn_global_load_lds(
        (const __attribute__((address_space(1))) void*)g,
        (__attribute__((address_space(3))) void*)l, 16, 0, 0);
}

// XOR swizzle of 16B k-segments per row; fragment reads <=2-way (free)
__device__ __forceinline__ int swz(int row) { return (row + (row >> 2)) & 3; }

// ------------------------ weight convert -----------------------------------
// src [Kreal, srcN] fp32 row-major -> dst [srcN][dstStride] fp16 (transposed).

struct CDesc {
    const float* src;
    __half* dst;
    int Kreal, Kpad, srcN, tile0, dstStride;
};
struct CTab {
    CDesc d[8];
    int nd;
};

__device__ void convert_body(const CTab& tab, int bid) {
    int idx = 0;
    for (int i = 1; i < tab.nd; ++i)
        if (tab.d[i].tile0 <= bid) idx = i;
    const CDesc d = tab.d[idx];
    const int q = bid - d.tile0;
    const int ntN = d.srcN >> 6;
    const int kb = (q / ntN) * 32;
    const int nb = (q % ntN) * 64;
    const int n = nb + (threadIdx.x & 63);
    const int k0 = kb + (threadIdx.x >> 6) * 8;
    h8 v;
#pragma unroll
    for (int j = 0; j < 8; ++j) {
        int k = k0 + j;
        v[j] = (_Float16)((k < d.Kreal) ? d.src[(size_t)k * d.srcN + n] : 0.f);
    }
    *reinterpret_cast<h8*>(&d.dst[(size_t)n * d.dstStride + k0]) = v;
}

// ----------------------- folded bias vectors -------------------------------

struct BDesc { float* out; const float* base; const float* v1; const float* B1;
               const float* v2; const float* B2; };
struct BTab { BDesc d[31]; };

// ------------------- batched fold GEMM tile --------------------------------
// M^T[n][k] = sum_j srcA^T[n][j] * U2[k][j]  (srcA fp32 [256 j][256 n], read
// transposed+cvt in-stage; U2 fp32 [256 k][256 j], cvt in-stage). Writes fp16
// plane at dst[n*stride + k].

#define ASTR 40

struct FDesc { const float* U2; const float* srcA; __half* dst; int stride; };
struct FTab { FDesc d[22]; };

__device__ void fold_tile(unsigned char* ldsraw, const FDesc& dd, int t4) {
    _Float16* Ah = (_Float16*)ldsraw;
    _Float16* Bh = (_Float16*)(ldsraw + 64 * ASTR * 2);
    const int rowBase = (t4 >> 2) * 64;
    const int colBase = (t4 & 3) * 64;

    const int tid = threadIdx.x;
    const int lane = tid & 63;
    const int wave = tid >> 6;
    const int waveM = (wave >> 1) * 32;
    const int waveN = (wave & 1) * 32;
    const int m0 = lane & 15;
    const int quad = lane >> 4;
    const int sr = tid >> 2;
    const int sseg = tid & 3;

    const f32x4 z = {0.f, 0.f, 0.f, 0.f};
    f32x4 acc[2][2] = {{z, z}, {z, z}};

    for (int kb = 0; kb < 256; kb += 32) {
        {
            // A: fb[n][k] = srcA[k][n]; strided fp32 reads + cvt
            const float* Ap = dd.srcA + (size_t)(kb + sseg * 8) * 256 + rowBase + sr;
            h8 v;
#pragma unroll
            for (int j = 0; j < 8; ++j) v[j] = (_Float16)Ap[(size_t)j * 256];
            *reinterpret_cast<h8*>(&Ah[sr * ASTR + sseg * 8]) = v;
        }
        {
            const float* Bp = dd.U2 + (size_t)(colBase + sr) * 256 + kb + sseg * 8;
            float4 u0 = *reinterpret_cast<const float4*>(Bp);
            float4 u1 = *reinterpret_cast<const float4*>(Bp + 4);
            h8 v;
            v[0] = (_Float16)u0.x; v[1] = (_Float16)u0.y;
            v[2] = (_Float16)u0.z; v[3] = (_Float16)u0.w;
            v[4] = (_Float16)u1.x; v[5] = (_Float16)u1.y;
            v[6] = (_Float16)u1.z; v[7] = (_Float16)u1.w;
            *reinterpret_cast<h8*>(&Bh[sr * ASTR + sseg * 8]) = v;
        }
        __syncthreads();

        const h8 a0 = *reinterpret_cast<const h8*>(&Ah[(waveM + m0) * ASTR + quad * 8]);
        const h8 a1 = *reinterpret_cast<const h8*>(&Ah[(waveM + 16 + m0) * ASTR + quad * 8]);
        const h8 b0 = *reinterpret_cast<const h8*>(&Bh[(waveN + m0) * ASTR + quad * 8]);
        const h8 b1 = *reinterpret_cast<const h8*>(&Bh[(waveN + 16 + m0) * ASTR + quad * 8]);

        acc[0][0] = __builtin_amdgcn_mfma_f32_16x16x32_f16(a0, b0, acc[0][0], 0, 0, 0);
        acc[0][1] = __builtin_amdgcn_mfma_f32_16x16x32_f16(a0, b1, acc[0][1], 0, 0, 0);
        acc[1][0] = __builtin_amdgcn_mfma_f32_16x16x32_f16(a1, b0, acc[1][0], 0, 0, 0);
        acc[1][1] = __builtin_amdgcn_mfma_f32_16x16x32_f16(a1, b1, acc[1][1], 0, 0, 0);

        __syncthreads();
    }

#pragma unroll
    for (int tm = 0; tm < 2; ++tm)
#pragma unroll
        for (int reg = 0; reg < 4; ++reg) {
            int n = rowBase + waveM + tm * 16 + quad * 4 + reg;
#pragma unroll
            for (int tn = 0; tn < 2; ++tn) {
                int k = colBase + waveN + tn * 16 + m0;
                dd.dst[(size_t)n * dd.stride + k] = __float2half_rn(acc[tm][tn][reg]);
            }
        }
}

// ----------------------- embed tile (self-converting) ----------------------
// out[row][col] = sum_{k<62} atom[row][k] * emb_w[k][col] + emb_b[col].
// K=64 padded (2 kb-iters). A cvt from atom fp32 (row-contiguous); B cvt from
// emb_w fp32 (strided, like convert_body). Block = 64 rows x 64 cols.

__device__ void embed_tile(unsigned char* ldsraw, int bx, int by,
                           const float* __restrict__ atom,
                           const float* __restrict__ emb_w,
                           const float* __restrict__ emb_b,
                           __half* __restrict__ outX, int M) {
    _Float16* Ah = (_Float16*)ldsraw;
    _Float16* Bh = (_Float16*)(ldsraw + 64 * ASTR * 2);
    const int rowBase = bx * 64;
    const int colBase = by * 64;

    const int tid = threadIdx.x;
    const int lane = tid & 63;
    const int wave = tid >> 6;
    const int waveM = (wave >> 1) * 32;
    const int waveN = (wave & 1) * 32;
    const int m0 = lane & 15;
    const int quad = lane >> 4;
    const int sr = tid >> 2;
    const int sseg = tid & 3;

    const f32x4 z = {0.f, 0.f, 0.f, 0.f};
    f32x4 acc[2][2] = {{z, z}, {z, z}};

    for (int kb = 0; kb < 64; kb += 32) {
        {
            const int arow = min(rowBase + sr, M - 1);
            h8 v;
#pragma unroll
            for (int j = 0; j < 8; ++j) {
                int k = kb + sseg * 8 + j;
                v[j] = (_Float16)((k < 62) ? atom[(size_t)arow * 62 + k] : 0.f);
            }
            *reinterpret_cast<h8*>(&Ah[sr * ASTR + sseg * 8]) = v;
        }
        {
            h8 v;
#pragma unroll
            for (int j = 0; j < 8; ++j) {
                int k = kb + sseg * 8 + j;
                v[j] = (_Float16)((k < 62) ? emb_w[(size_t)k * 256 + colBase + sr] : 0.f);
            }
            *reinterpret_cast<h8*>(&Bh[sr * ASTR + sseg * 8]) = v;
        }
        __syncthreads();

        const h8 a0 = *reinterpret_cast<const h8*>(&Ah[(waveM + m0) * ASTR + quad * 8]);
        const h8 a1 = *reinterpret_cast<const h8*>(&Ah[(waveM + 16 + m0) * ASTR + quad * 8]);
        const h8 b0 = *reinterpret_cast<const h8*>(&Bh[(waveN + m0) * ASTR + quad * 8]);
        const h8 b1 = *reinterpret_cast<const h8*>(&Bh[(waveN + 16 + m0) * ASTR + quad * 8]);

        acc[0][0] = __builtin_amdgcn_mfma_f32_16x16x32_f16(a0, b0, acc[0][0], 0, 0, 0);
        acc[0][1] = __builtin_amdgcn_mfma_f32_16x16x32_f16(a0, b1, acc[0][1], 0, 0, 0);
        acc[1][0] = __builtin_amdgcn_mfma_f32_16x16x32_f16(a1, b0, acc[1][0], 0, 0, 0);
        acc[1][1] = __builtin_amdgcn_mfma_f32_16x16x32_f16(a1, b1, acc[1][1], 0, 0, 0);

        __syncthreads();
    }

#pragma unroll
    for (int tm = 0; tm < 2; ++tm)
#pragma unroll
        for (int reg = 0; reg < 4; ++reg) {
            int row = rowBase + waveM + tm * 16 + quad * 4 + reg;
            if (row >= M) continue;
#pragma unroll
            for (int tn = 0; tn < 2; ++tn) {
                int col = colBase + waveN + tn * 16 + m0;
                outX[(size_t)row * 256 + col] =
                    __float2half_rn(acc[tm][tn][reg] + emb_b[col]);
            }
        }
}

// ---- K2: scatter(buckets) + fold-direct + bias vecs + converts + embed ----

__global__ __launch_bounds__(256) void setup_kernel(
    const int* __restrict__ src, const int* __restrict__ dst,
    int* __restrict__ cnt, int* __restrict__ csr_src,
    const float* __restrict__ ef, __half* __restrict__ ef8, int E, int sblocks,
    FTab ft, BTab bt, int fblocks, int bblocks, CTab ct, int cblocks,
    const float* __restrict__ atom, const float* __restrict__ emb_w,
    const float* __restrict__ emb_b, __half* __restrict__ outX,
    int M, int mblk64) {
    __shared__ __align__(16) unsigned char lds[16384];
    int b = blockIdx.x;
    if (b < sblocks) {
        int i = b * 256 + (int)threadIdx.x;
        if (i < E) {
            int d = dst[i];
            int pos = atomicAdd(&cnt[d], 1);
            size_t idx = (size_t)d * CAP + pos;
            csr_src[idx] = src[i];
            const float* s6 = ef + (size_t)i * 6;
            unsigned short h[8];
#pragma unroll
            for (int j = 0; j < 6; ++j) h[j] = __half_as_ushort(__float2half_rn(s6[j]));
            h[6] = 0; h[7] = 0;
            int4 pk;
            pk.x = (int)(h[0] | ((unsigned)h[1] << 16));
            pk.y = (int)(h[2] | ((unsigned)h[3] << 16));
            pk.z = (int)(h[4] | ((unsigned)h[5] << 16));
            pk.w = (int)(h[6] | ((unsigned)h[7] << 16));
            *reinterpret_cast<int4*>(ef8 + idx * 8) = pk;
        }
        return;
    }
    b -= sblocks;
    if (b < fblocks) {
        fold_tile(lds, ft.d[b >> 4], b & 15);
        return;
    }
    b -= fblocks;
    if (b < bblocks) {
        const BDesc d = bt.d[b];
        const int j = threadIdx.x;
        float acc = d.base ? d.base[j] : 0.f;
        if (d.v1)
            for (int k = 0; k < 256; ++k) acc = fmaf(d.v1[k], d.B1[(size_t)k * 256 + j], acc);
        if (d.v2)
            for (int k = 0; k < 256; ++k) acc = fmaf(d.v2[k], d.B2[(size_t)k * 256 + j], acc);
        d.out[j] = acc;
        return;
    }
    b -= bblocks;
    if (b < cblocks) {
        convert_body(ct, b);
        return;
    }
    b -= cblocks;
    embed_tile(lds, b % mblk64, b / mblk64, atom, emb_w, emb_b, outX, M);
}

// ------------------------------ MFMA GEMM ----------------------------------
// C = act( [A|A2]@W + bias + rowscale.*bias2 ), fp16 in/out, fp32 acc.
// A covers k<256, A2 (optional) covers k>=256 (both row-stride lda).
// Tile 64 x (TN*32), BK=32, 4 waves 2x2. Double-buffered K-loop.

template <int TN>
__global__ __launch_bounds__(256) void mfma_gemm(
    const __half* __restrict__ A, int lda, const __half* __restrict__ A2,
    const __half* __restrict__ W, int K,
    const float* __restrict__ bias, const float* __restrict__ bias2,
    const float* __restrict__ rowscale,
    __half* __restrict__ C, int M, int Nc, int do_relu) {
    constexpr int BUF = 4096 + TN * 2048;
    __shared__ __align__(16) unsigned char lds[2 * BUF];

    const int tid = threadIdx.x;
    const int lane = tid & 63;
    const int wave = tid >> 6;
    const int m0 = lane & 15;
    const int quad = lane >> 4;
    const int waveM = (wave >> 1) * 32;
    const int waveN = (wave & 1) * (TN * 16);
    const int rowBase = blockIdx.x * 64;
    const int colBase = blockIdx.y * (TN * 32);

    const int sa_r = tid >> 2;
    const int sa_ks = (tid & 3) ^ swz(sa_r);
    const int sa_row = min(rowBase + sa_r, M - 1);
    const int sb_r1 = sa_r + 64;
    const int sb_ks1 = (tid & 3) ^ swz(sb_r1);

    int aoff[2], boff[TN];
#pragma unroll
    for (int tm = 0; tm < 2; ++tm) {
        int r = waveM + tm * 16 + m0;
        aoff[tm] = ((r << 2) + (quad ^ swz(r))) << 4;
    }
#pragma unroll
    for (int tn = 0; tn < TN; ++tn) {
        int r = waveN + tn * 16 + m0;
        boff[tn] = 4096 + (((r << 2) + (quad ^ swz(r))) << 4);
    }

    const f32x4 z = {0.f, 0.f, 0.f, 0.f};
    f32x4 acc[2][TN];
#pragma unroll
    for (int tm = 0; tm < 2; ++tm)
#pragma unroll
        for (int tn = 0; tn < TN; ++tn) acc[tm][tn] = z;

    const __half* ga = A + (size_t)sa_row * lda + sa_ks * 8;
    const __half* ga2 = A2 ? A2 + (size_t)sa_row * lda + sa_ks * 8 : nullptr;
    const __half* gb0 = W + (size_t)(colBase + sa_r) * K + sa_ks * 8;
    const __half* gb1 = W + (size_t)(colBase + sb_r1) * K + sb_ks1 * 8;

    auto issue = [&](int p, int kb) {
        unsigned char* base = lds + p * BUF;
        const __half* as = (A2 && kb >= 256) ? (ga2 + (kb - 256)) : (ga + kb);
        gld16(as, base + wave * 1024);
        gld16(gb0 + kb, base + 4096 + wave * 1024);
        if constexpr (TN == 4) gld16(gb1 + kb, base + 8192 + wave * 1024);
    };

    issue(0, 0);
    int p = 0;
    for (int kb = 0; kb < K; kb += 32) {
        const bool has_next = (kb + 32 < K);
        if (has_next) issue(p ^ 1, kb + 32);
        if (has_next) {
            if constexpr (TN == 4)
                asm volatile("s_waitcnt vmcnt(3)" ::: "memory");
            else
                asm volatile("s_waitcnt vmcnt(2)" ::: "memory");
        } else {
            asm volatile("s_waitcnt vmcnt(0)" ::: "memory");
        }
        asm volatile("s_barrier" ::: "memory");

        const unsigned char* base = lds + p * BUF;
        h8 ah[2], bh[TN];
#pragma unroll
        for (int tm = 0; tm < 2; ++tm)
            ah[tm] = *reinterpret_cast<const h8*>(base + aoff[tm]);
#pragma unroll
        for (int tn = 0; tn < TN; ++tn)
            bh[tn] = *reinterpret_cast<const h8*>(base + boff[tn]);
#pragma unroll
        for (int tm = 0; tm < 2; ++tm)
#pragma unroll
            for (int tn = 0; tn < TN; ++tn)
                acc[tm][tn] = __builtin_amdgcn_mfma_f32_16x16x32_f16(
                    ah[tm], bh[tn], acc[tm][tn], 0, 0, 0);
        asm volatile("s_waitcnt lgkmcnt(0)" ::: "memory");
        asm volatile("s_barrier" ::: "memory");
        p ^= 1;
    }

    // epilogue
    float cb[TN], db[TN];
    int col[TN];
#pragma unroll
    for (int tn = 0; tn < TN; ++tn) {
        col[tn] = colBase + waveN + tn * 16 + m0;
        cb[tn] = bias ? bias[col[tn]] : 0.f;
        db[tn] = bias2 ? bias2[col[tn]] : 0.f;
    }
#pragma unroll
    for (int tm = 0; tm < 2; ++tm) {
#pragma unroll
        for (int reg = 0; reg < 4; ++reg) {
            int row = rowBase + waveM + tm * 16 + quad * 4 + reg;
            if (row >= M) continue;
            float rs = rowscale ? rowscale[row] : 0.0f;
#pragma unroll
            for (int tn = 0; tn < TN; ++tn) {
                float v = acc[tm][tn][reg] + cb[tn] + rs * db[tn];
                if (do_relu) v = fmaxf(v, 0.f);
                C[(size_t)row * Nc + col[tn]] = __float2half_rn(v);
            }
        }
    }
}

// --------------------------- edge aggregation ------------------------------
// Hagg[v] = sum_{e=(s,v)} relu(P[s] + Q[v] + ef_e @ W1c); bagg pre-added to
// Q by the PQ GEMM bias. PQ fp16 [N][512]. Bucketed edges: node v's edges at
// [v*CAP, v*CAP+cnt[v]). One wave/node, 4 ch/lane. degf_out (layer 0 only)
// records float degree for the UPD rowscale.

__global__ __launch_bounds__(256) void aggregate_kernel(
    const __half* __restrict__ PQ, const __half* __restrict__ ef8,
    const int* __restrict__ cnt, const int* __restrict__ csr_src,
    const float* __restrict__ W1c, __half* __restrict__ Hagg,
    float* __restrict__ degf_out, int n) {
    const int wave = threadIdx.x >> 6;
    const int lane = threadIdx.x & 63;
    const int node = blockIdx.x * 4 + wave;
    if (node >= n) return;
    const int ch = lane * 4;  // 64 lanes x 4 ch = 256

    float wc[6][4];
#pragma unroll
    for (int k = 0; k < 6; ++k) {
        float4 w0 = *reinterpret_cast<const float4*>(W1c + k * HID + ch);
        wc[k][0] = w0.x; wc[k][1] = w0.y; wc[k][2] = w0.z; wc[k][3] = w0.w;
    }
    float qb[4];
    unpack_h4(*reinterpret_cast<const int2*>(PQ + (size_t)node * 512 + 256 + ch), qb);

    float acc[4] = {0.f, 0.f, 0.f, 0.f};

    auto fma_edge = [&](const int2& praw, const int4& eraw) {
        float p[4], e[8];
        unpack_h4(praw, p);
        unpack_h8(eraw, e);
#pragma unroll
        for (int i = 0; i < 4; ++i) {
            float h = p[i] + qb[i];
            h = fmaf(e[0], wc[0][i], h);
            h = fmaf(e[1], wc[1][i], h);
            h = fmaf(e[2], wc[2][i], h);
            h = fmaf(e[3], wc[3][i], h);
            h = fmaf(e[4], wc[4][i], h);
            h = fmaf(e[5], wc[5][i], h);
            acc[i] += fmaxf(h, 0.f);
        }
    };

    const int beg = node * CAP;
    const int deg = cnt[node];
    const int end = beg + deg;
    if (degf_out && lane == 0) degf_out[node] = (float)deg;
    int j = beg;

    while (j + 6 <= end) {
        int s0 = csr_src[j];
        int s1 = csr_src[j + 1];
        int s2 = csr_src[j + 2];
        int s3 = csr_src[j + 3];
        int s4 = csr_src[j + 4];
        int s5 = csr_src[j + 5];
        int4 e0 = *reinterpret_cast<const int4*>(ef8 + (size_t)j * 8);
        int4 e1 = *reinterpret_cast<const int4*>(ef8 + (size_t)(j + 1) * 8);
        int4 e2 = *reinterpret_cast<const int4*>(ef8 + (size_t)(j + 2) * 8);
        int4 e3 = *reinterpret_cast<const int4*>(ef8 + (size_t)(j + 3) * 8);
        int4 e4 = *reinterpret_cast<const int4*>(ef8 + (size_t)(j + 4) * 8);
        int4 e5 = *reinterpret_cast<const int4*>(ef8 + (size_t)(j + 5) * 8);
        int2 p0 = *reinterpret_cast<const int2*>(PQ + (size_t)s0 * 512 + ch);
        int2 p1 = *reinterpret_cast<const int2*>(PQ + (size_t)s1 * 512 + ch);
        int2 p2 = *reinterpret_cast<const int2*>(PQ + (size_t)s2 * 512 + ch);
        int2 p3 = *reinterpret_cast<const int2*>(PQ + (size_t)s3 * 512 + ch);
        int2 p4 = *reinterpret_cast<const int2*>(PQ + (size_t)s4 * 512 + ch);
        int2 p5 = *reinterpret_cast<const int2*>(PQ + (size_t)s5 * 512 + ch);
        fma_edge(p0, e0);
        fma_edge(p1, e1);
        fma_edge(p2, e2);
        fma_edge(p3, e3);
        fma_edge(p4, e4);
        fma_edge(p5, e5);
        j += 6;
    }
    while (j + 2 <= end) {
        int s0 = csr_src[j];
        int s1 = csr_src[j + 1];
        int4 e0 = *reinterpret_cast<const int4*>(ef8 + (size_t)j * 8);
        int4 e1 = *reinterpret_cast<const int4*>(ef8 + (size_t)(j + 1) * 8);
        int2 p0 = *reinterpret_cast<const int2*>(PQ + (size_t)s0 * 512 + ch);
        int2 p1 = *reinterpret_cast<const int2*>(PQ + (size_t)s1 * 512 + ch);
        fma_edge(p0, e0);
        fma_edge(p1, e1);
        j += 2;
    }
    if (j < end) {
        int s = csr_src[j];
        int4 e = *reinterpret_cast<const int4*>(ef8 + (size_t)j * 8);
        int2 pw = *reinterpret_cast<const int2*>(PQ + (size_t)s * 512 + ch);
        fma_edge(pw, e);
    }

    unsigned short hs[4];
#pragma unroll
    for (int i = 0; i < 4; ++i) hs[i] = __half_as_ushort(__float2half_rn(acc[i]));
    int2 pk;
    pk.x = (int)(hs[0] | ((unsigned)hs[1] << 16));
    pk.y = (int)(hs[2] | ((unsigned)hs[3] << 16));
    *reinterpret_cast<int2*>(Hagg + (size_t)node * HID + ch) = pk;
}

// --------------------------- fused readout ---------------------------------
// h1 = relu(U5@wF + cbF) -> LDS (stride 272 halves); h2 = relu(h1@wR2 + bR2);
// s += h2 . w3 per row; block reduce; atomicAdd; done-counter finalize.

__global__ __launch_bounds__(256) void readout_kernel(
    const __half* __restrict__ U5, const __half* __restrict__ wF,
    const float* __restrict__ cbF, const __half* __restrict__ wR2,
    const float* __restrict__ bR2, const float* __restrict__ w3,
    const float* __restrict__ b3, float* __restrict__ accum,
    int* __restrict__ done, float* __restrict__ outp, int M, int nblocks) {
    __shared__ __align__(16) unsigned char lds[24576 + 64 * 272 * 2];
    _Float16* h1 = (_Float16*)(lds + 24576);

    const int tid = threadIdx.x;
    const int lane = tid & 63;
    const int wave = tid >> 6;
    const int m0 = lane & 15;
    const int quad = lane >> 4;
    const int waveM = (wave >> 1) * 32;
    const int waveN = (wave & 1) * 64;
    const int rowBase = blockIdx.x * 64;

    const int sa_r = tid >> 2;
    const int sa_ks = (tid & 3) ^ swz(sa_r);
    const int sa_row = min(rowBase + sa_r, M - 1);
    const int sb_r1 = sa_r + 64;
    const int sb_ks1 = (tid & 3) ^ swz(sb_r1);

    int aoff[2], boff[4];
#pragma unroll
    for (int tm = 0; tm < 2; ++tm) {
        int r = waveM + tm * 16 + m0;
        aoff[tm] = ((r << 2) + (quad ^ swz(r))) << 4;
    }
#pragma unroll
    for (int tn = 0; tn < 4; ++tn) {
        int r = waveN + tn * 16 + m0;
        boff[tn] = (((r << 2) + (quad ^ swz(r))) << 4);
    }

    constexpr int BUF = 4096 + 4 * 2048;
    const f32x4 z = {0.f, 0.f, 0.f, 0.f};

    for (int half = 0; half < 2; ++half) {
        const __half* W = wF + (size_t)(half * 128) * 256;
        f32x4 acc[2][4] = {{z, z, z, z}, {z, z, z, z}};
        const __half* ga = U5 + (size_t)sa_row * 256 + sa_ks * 8;
        const __half* gb0 = W + (size_t)sa_r * 256 + sa_ks * 8;
        const __half* gb1 = W + (size_t)sb_r1 * 256 + sb_ks1 * 8;

        auto issue = [&](int p, int kb) {
            unsigned char* base = lds + p * BUF;
            gld16(ga + kb, base + wave * 1024);
            gld16(gb0 + kb, base + 4096 + wave * 1024);
            gld16(gb1 + kb, base + 8192 + wave * 1024);
        };
        issue(0, 0);
        int p = 0;
        for (int kb = 0; kb < 256; kb += 32) {
            const bool has_next = (kb + 32 < 256);
            if (has_next) issue(p ^ 1, kb + 32);
            if (has_next) asm volatile("s_waitcnt vmcnt(3)" ::: "memory");
            else asm volatile("s_waitcnt vmcnt(0)" ::: "memory");
            asm volatile("s_barrier" ::: "memory");
            const unsigned char* base = lds + p * BUF;
            h8 ah[2], bh[4];
#pragma unroll
            for (int tm = 0; tm < 2; ++tm)
                ah[tm] = *reinterpret_cast<const h8*>(base + aoff[tm]);
#pragma unroll
            for (int tn = 0; tn < 4; ++tn)
                bh[tn] = *reinterpret_cast<const h8*>(base + 4096 + boff[tn]);
#pragma unroll
            for (int tm = 0; tm < 2; ++tm)
#pragma unroll
                for (int tn = 0; tn < 4; ++tn)
                    acc[tm][tn] = __builtin_amdgcn_mfma_f32_16x16x32_f16(
                        ah[tm], bh[tn], acc[tm][tn], 0, 0, 0);
            asm volatile("s_waitcnt lgkmcnt(0)" ::: "memory");
            asm volatile("s_barrier" ::: "memory");
            p ^= 1;
        }
#pragma unroll
        for (int tm = 0; tm < 2; ++tm)
#pragma unroll
            for (int reg = 0; reg < 4; ++reg) {
                int r = waveM + tm * 16 + quad * 4 + reg;
#pragma unroll
                for (int tn = 0; tn < 4; ++tn) {
                    int c = half * 128 + waveN + tn * 16 + m0;
                    float v = acc[tm][tn][reg] + cbF[c];
                    h1[r * 272 + c] = (_Float16)fmaxf(v, 0.f);
                }
            }
        __syncthreads();
    }

    f32x4 acc2[2][4] = {{z, z, z, z}, {z, z, z, z}};
    auto issueB = [&](int p, int kb) {
        unsigned char* base = lds + p * 8192;
        gld16(wR2 + (size_t)sa_r * 256 + sa_ks * 8 + kb, base + wave * 1024);
        gld16(wR2 + (size_t)sb_r1 * 256 + sb_ks1 * 8 + kb, base + 4096 + wave * 1024);
    };
    issueB(0, 0);
    int p = 0;
    for (int kb = 0; kb < 256; kb += 32) {
        const bool has_next = (kb + 32 < 256);
        if (has_next) issueB(p ^ 1, kb + 32);
        if (has_next) asm volatile("s_waitcnt vmcnt(2)" ::: "memory");
        else asm volatile("s_waitcnt vmcnt(0)" ::: "memory");
        asm volatile("s_barrier" ::: "memory");
        const unsigned char* base = lds + p * 8192;
        h8 ah[2], bh[4];
#pragma unroll
        for (int tm = 0; tm < 2; ++tm)
            ah[tm] = *reinterpret_cast<const h8*>(
                &h1[(waveM + tm * 16 + m0) * 272 + kb + quad * 8]);
#pragma unroll
        for (int tn = 0; tn < 4; ++tn)
            bh[tn] = *reinterpret_cast<const h8*>(base + boff[tn]);
#pragma unroll
        for (int tm = 0; tm < 2; ++tm)
#pragma unroll
            for (int tn = 0; tn < 4; ++tn)
                acc2[tm][tn] = __builtin_amdgcn_mfma_f32_16x16x32_f16(
                    ah[tm], bh[tn], acc2[tm][tn], 0, 0, 0);
        asm volatile("s_waitcnt lgkmcnt(0)" ::: "memory");
        asm volatile("s_barrier" ::: "memory");
        p ^= 1;
    }

    float s = 0.f;
#pragma unroll
    for (int tm = 0; tm < 2; ++tm)
#pragma unroll
        for (int reg = 0; reg < 4; ++reg) {
            int row = rowBase + waveM + tm * 16 + quad * 4 + reg;
            if (row >= M) continue;
#pragma unroll
            for (int tn = 0; tn < 4; ++tn) {
                int c = waveN + tn * 16 + m0;
                float v = acc2[tm][tn][reg] + bR2[c];
                s += fmaxf(v, 0.f) * w3[c];
            }
        }
    __syncthreads();
    float* red = (float*)lds;
    red[tid] = s;
    __syncthreads();
    for (int off = 128; off > 0; off >>= 1) {
        if (tid < off) red[tid] += red[tid + off];
        __syncthreads();
    }
    if (tid == 0) {
        atomicAdd(accum, red[0]);
        __threadfence();
        int old = atomicAdd(done, 1);
        if (old == nblocks - 1) {
            float tot = atomicAdd(accum, 0.0f);
            outp[0] = tot / (float)M + b3[0];
        }
    }
}

// ------------------------------- driver ------------------------------------

extern "C" void kernel_launch(void* const* d_in, const int* in_sizes, int n_in,
                              void* d_out, int out_size, void* d_ws, size_t ws_size,
                              hipStream_t stream) {
    const float* atom   = (const float*)d_in[0];
    const int*   eidx   = (const int*)d_in[1];
    const float* ef     = (const float*)d_in[2];
    const float* emb_w  = (const float*)d_in[3];
    const float* emb_b  = (const float*)d_in[4];
    const float* msg_w1 = (const float*)d_in[5];
    const float* msg_b1 = (const float*)d_in[6];
    const float* msg_w2 = (const float*)d_in[7];
    const float* msg_b2 = (const float*)d_in[8];
    const float* upd_w1 = (const float*)d_in[9];
    const float* upd_b1 = (const float*)d_in[10];
    const float* upd_w2 = (const float*)d_in[11];
    const float* upd_b2 = (const float*)d_in[12];
    const float* r_w1   = (const float*)d_in[13];
    const float* r_b1   = (const float*)d_in[14];
    const float* r_w2   = (const float*)d_in[15];
    const float* r_b2   = (const float*)d_in[16];
    const float* r_w3   = (const float*)d_in[17];
    const float* r_b3   = (const float*)d_in[18];

    const int N = in_sizes[0] / 62;
    const int E = in_sizes[1] / 2;
    const int L = in_sizes[5] / (518 * 256);
    const int* src = eidx;
    const int* dst = eidx + E;

    char* wp = (char*)d_ws;
    auto alloc = [&](size_t bytes) -> void* {
        void* p = (void*)wp;
        wp += (bytes + 255) & ~(size_t)255;
        return p;
    };
    int*   cnt     = (int*)alloc((size_t)N * 4);
    float* accum   = (float*)alloc(256);
    int*   done    = (int*)((char*)accum + 16);
    size_t zero_bytes = (size_t)((char*)accum - (char*)d_ws) + 256;
    float* degf    = (float*)alloc((size_t)N * 4);
    int*   csr_src = (int*)alloc((size_t)N * CAP * 4);
    __half* ef8    = (__half*)alloc((size_t)N * CAP * 8 * 2);

    const int SQ_P = 256 * 256;
    __half* w_r2  = (__half*)alloc((size_t)128 * 256 * 2);
    __half* wF    = (__half*)alloc((size_t)SQ_P * 2);
    __half *wPQ[6], *wUPD[6];
    for (int l = 0; l < L; ++l) {
        wPQ[l]  = (__half*)alloc((size_t)512 * 256 * 2);  // [512 cols][K=256]
        wUPD[l] = (__half*)alloc((size_t)256 * 512 * 2);  // [256 cols][K=512] = [wM3;wR]
    }
    float* bvec = (float*)alloc((size_t)19 * 256 * 4);
    float* b512 = (float*)alloc((size_t)L * 512 * 4);

    __half* bufX0 = (__half*)alloc((size_t)N * HID * 2);
    __half* bufX1 = (__half*)alloc((size_t)N * HID * 2);
    __half* PQ    = (__half*)alloc((size_t)N * 512 * 2);
    __half* HaggH = (__half*)alloc((size_t)N * HID * 2);

    hipMemsetAsync(d_ws, 0, zero_bytes, stream);

    // ---- direct-use converts (run inside K2; consumers are post-K2) ----
    CTab ct;
    int nd = 0, ctiles = 0;
    auto addDesc = [&](const float* s, __half* dh, int Kreal, int Kpad, int srcN,
                       int dstStride) {
        ct.d[nd] = {s, dh, Kreal, Kpad, srcN, ctiles, dstStride};
        ctiles += (Kpad / 32) * (srcN / 64);
        ++nd;
    };
    addDesc(msg_w1, wPQ[0], 256, 256, 256, 256);                     // P l=0
    addDesc(msg_w1 + 256 * 256, wPQ[0] + SQ_P, 256, 256, 256, 256);  // Q l=0
    addDesc(upd_w1, wUPD[0] + 256, 256, 256, 256, 512);              // R l=0 -> hi-K
    addDesc(r_w2, w_r2, 256, 256, 128, 256);
    ct.nd = nd;

    // ---- fold GEMM descriptors (A = raw fp32 source, cvt in-stage) ----
    FTab ft;
    for (int l = 1; l < L; ++l) {
        const float* U2p = upd_w2 + (size_t)(l - 1) * SQ_P;
        ft.d[l - 1] = {U2p, msg_w1 + (size_t)l * 518 * 256, wPQ[l], 256};
        ft.d[4 + l] = {U2p, msg_w1 + (size_t)l * 518 * 256 + 256 * 256,
                       wPQ[l] + SQ_P, 256};
        ft.d[9 + l] = {U2p, upd_w1 + (size_t)l * 512 * 256, wUPD[l] + 256, 512};
    }
    for (int l = 0; l < L; ++l)
        ft.d[15 + l] = {msg_w2 + (size_t)l * SQ_P,
                        upd_w1 + (size_t)l * 512 * 256 + 256 * 256, wUPD[l], 512};
    ft.d[21] = {upd_w2 + (size_t)5 * SQ_P, r_w1, wF, 256};

    BTab bt;
    int nb = 0;
    for (int l = 0; l < L; ++l) {
        const float* ub2p = (l > 0) ? upd_b2 + (size_t)(l - 1) * 256 : nullptr;
        bt.d[nb++] = {b512 + (size_t)l * 512 + 256, msg_b1 + (size_t)l * 256,
                      ub2p, msg_w1 + (size_t)l * 518 * 256,
                      ub2p, msg_w1 + (size_t)l * 518 * 256 + 256 * 256};
        bt.d[nb++] = {b512 + (size_t)l * 512, nullptr, nullptr, nullptr, nullptr, nullptr};
        bt.d[nb++] = {bvec + (size_t)(6 + l) * 256, upd_b1 + (size_t)l * 256,
                      ub2p, upd_w1 + (size_t)l * 512 * 256, nullptr, nullptr};
        bt.d[nb++] = {bvec + (size_t)(12 + l) * 256, nullptr,
                      msg_b2 + (size_t)l * 256, upd_w1 + (size_t)l * 512 * 256 + 256 * 256,
                      nullptr, nullptr};
    }
    bt.d[nb++] = {bvec + (size_t)18 * 256, r_b1, upd_b2 + (size_t)5 * 256, r_w1,
                  nullptr, nullptr};

    // ---- K2: scatter + fold-direct + bias + converts + embed-direct ----
    const int sblocks = (E + 255) / 256;
    const int fblocks = 22 * 16;
    const int mblk64 = (N + 63) / 64;
    const int grid2 = sblocks + fblocks + nb + ctiles + mblk64 * 4;
    setup_kernel<<<grid2, 256, 0, stream>>>(
        src, dst, cnt, csr_src, ef, ef8, E, sblocks,
        ft, bt, fblocks, nb, ct, ctiles,
        atom, emb_w, emb_b, bufX0, N, mblk64);

    // ---- layers (64-row tiles, 628-block grids) ----
    dim3 blk(256);
    __half* U_prev = bufX0;
    __half* U_next = bufX1;
    for (int l = 0; l < L; ++l) {
        const float* w1c = msg_w1 + (size_t)l * 518 * 256 + 512 * 256;

        // PQ = U_prev @ [M1a|M1b] + [0|bagg]   (512 cols)
        mfma_gemm<4><<<dim3(mblk64, 4), blk, 0, stream>>>(
            U_prev, HID, nullptr, wPQ[l], HID,
            b512 + (size_t)l * 512, nullptr, nullptr,
            PQ, N, 512, 0);
        aggregate_kernel<<<(N + 3) / 4, blk, 0, stream>>>(
            PQ, ef8, cnt, csr_src, w1c, HaggH, (l == 0) ? degf : nullptr, N);
        // U_next = relu([Hagg|U_prev] @ [wM3;wR] + b + deg.*b2)   (K=512)
        mfma_gemm<2><<<dim3(mblk64, 4), blk, 0, stream>>>(
            HaggH, HID, U_prev, wUPD[l], 512,
            bvec + (size_t)(6 + l) * 256, bvec + (size_t)(12 + l) * 256, degf,
            U_next, N, 256, 1);
        __half* t = U_prev; U_prev = U_next; U_next = t;
    }

    // fused readout
    readout_kernel<<<mblk64, blk, 0, stream>>>(
        U_prev, wF, bvec + (size_t)18 * 256, w_r2, r_b2, r_w3, r_b3,
        accum, done, (float*)d_out, N, mblk64);
}